// Round 8
// baseline (137.839 us; speedup 1.0000x reference)
//
#include <hip/hip_runtime.h>
#include <hip/hip_bf16.h>
#include <math.h>

#define NB 512
#define NQ 30
#define ND 512
#define NE 128
#define NK 21
#define VOCAB 50000

typedef __attribute__((ext_vector_type(4))) float f32x4;
typedef __attribute__((ext_vector_type(8))) short short8;

#define AS1C(p) ((const __attribute__((address_space(1))) unsigned int*)(p))
#define AS3C(p) ((__attribute__((address_space(3))) unsigned int*)(p))

// normalized vocab table, bf16 (12.8 MB). Fully rewritten every launch (idempotent).
__device__ unsigned short g_norm[(size_t)VOCAB * NE];
// per-(b,dquarter) partials for ALL 21 kernels incl. exact-match count at k=20.
// Plain stores only, every element rewritten every launch. No atomics, no zeroing.
__device__ float g_Sp[(size_t)NB * 4 * NQ * NK];
// 256B of zeros for padding q-rows 30,31. Never written -> stays zero.
__device__ unsigned short g_zero[NE];

__device__ __forceinline__ unsigned short f2bf(float f) {
  unsigned int x = __builtin_bit_cast(unsigned int, f);
  x = (x + 0x7fffu + ((x >> 16) & 1u)) >> 16;   // RNE
  return (unsigned short)x;
}

// ---------------- kernel 1: normalize vocab to bf16 ----------------
__global__ __launch_bounds__(256) void norm_kernel(const float* __restrict__ emb) {
  const int t = threadIdx.x;
  const int row = blockIdx.x * 8 + (t >> 5);
  const int j = t & 31;
  const float* src = emb + (size_t)row * NE;
  float4 v = *(const float4*)(src + j * 4);
  float ssq = v.x * v.x + v.y * v.y + v.z * v.z + v.w * v.w;
  ssq += __shfl_xor(ssq, 1);
  ssq += __shfl_xor(ssq, 2);
  ssq += __shfl_xor(ssq, 4);
  ssq += __shfl_xor(ssq, 8);
  ssq += __shfl_xor(ssq, 16);
  const float sc = 1.0f / fmaxf(sqrtf(ssq), 1e-12f);
  ushort4 o;
  o.x = f2bf(v.x * sc); o.y = f2bf(v.y * sc);
  o.z = f2bf(v.z * sc); o.w = f2bf(v.w * sc);
  *(ushort4*)(g_norm + (size_t)row * NE + j * 4) = o;
}

// ---------------- kernel 2: partial KNRM (128 doc rows x 32 q per block) ----------------
// 512 threads = 8 waves; wave w: qt=w&1 (16 q), dg=w>>1 (32 d rows).
// LDS: dtile 32KB + qtile 8KB = 40960B -> 4 blocks/CU.
__global__ __launch_bounds__(512, 8) void knrm_part(
    const int* __restrict__ query, const int* __restrict__ doc)
{
  extern __shared__ unsigned char smem_raw[];
  unsigned short* dtile = (unsigned short*)smem_raw;   // [128][128] bf16, slot-swizzled
  unsigned short* qtile = dtile + 128 * NE;            // [32][128]  bf16, slot-swizzled

  const int t = threadIdx.x;
  // XCD swizzle: XCD x gets b in [x*64, (x+1)*64) contiguous. 2048 % 8 == 0 -> bijective.
  const unsigned bid = blockIdx.x;
  const unsigned swz = (bid & 7) * 256 + (bid >> 3);
  const int b  = swz >> 2;
  const int dq = swz & 3;
  const int d0 = dq * 128;

  const int wave = t >> 6, lane = t & 63;
  const int srow4 = lane >> 4, slot = lane & 15;

  // ---- stage 128 doc rows: 4 x global_load_lds(16B), zero VGPR payload ----
#pragma unroll
  for (int rnd = 0; rnd < 4; ++rnd) {
    const int r = rnd * 32 + wave * 4 + srow4;
    const int id = doc[b * ND + d0 + r];
    const unsigned short* src = g_norm + (size_t)id * NE + ((slot ^ (r & 7)) * 8);
    unsigned short* ldst = dtile + (rnd * 32 + wave * 4) * NE;  // wave-uniform
    __builtin_amdgcn_global_load_lds(AS1C(src), AS3C(ldst), 16, 0, 0);
  }
  // ---- stage 32 query rows (30 real + 2 zero), one round ----
  {
    const int qr = wave * 4 + srow4;
    const unsigned short* srcrow =
        (qr < NQ) ? (g_norm + (size_t)query[b * NQ + qr] * NE) : g_zero;
    const unsigned short* src = srcrow + ((slot ^ (qr & 7)) * 8);
    unsigned short* ldst = qtile + (wave * 4) * NE;             // wave-uniform
    __builtin_amdgcn_global_load_lds(AS1C(src), AS3C(ldst), 16, 0, 0);
  }
  __syncthreads();   // drains vmcnt -> tiles complete

  const int lrow = lane & 15, lgrp = lane >> 4;
  const int qt = wave & 1, dg = wave >> 1;

  // ---- mm^T tile: C[d][q]; A and B from swizzled LDS ----
  f32x4 acc[2];
  acc[0] = (f32x4){0.f, 0.f, 0.f, 0.f};
  acc[1] = (f32x4){0.f, 0.f, 0.f, 0.f};
  const int qrow = qt * 16 + lrow;
#pragma unroll
  for (int ks = 0; ks < 4; ++ks) {
    const int qs = (ks * 4 + lgrp) ^ (qrow & 7);
    short8 bq = *(const short8*)(qtile + qrow * NE + qs * 8);
#pragma unroll
    for (int dt = 0; dt < 2; ++dt) {
      const int R = dg * 32 + dt * 16 + lrow;
      const int as = (ks * 4 + lgrp) ^ (R & 7);
      short8 a = *(const short8*)(dtile + R * NE + as * 8);
      acc[dt] = __builtin_amdgcn_mfma_f32_16x16x32_bf16(a, bq, acc[dt], 0, 0, 0);
    }
  }
  __syncthreads();   // LDS tiles consumed -> reuse dtile region

  float* Sw  = (float*)dtile;        // [8 waves][16 lrow][20 k] = 10240 B
  float* Sex = Sw + 8 * 16 * 20;     // [32] exact-match counts (block-local)
  if (t < 32) Sex[t] = 0.0f;
  __syncthreads();

  // ---- exact-match kernel (mu=1, sigma=0.001): integer ID equality ----
  if (t < 128) {
    const int did = doc[b * ND + d0 + t];
    const int* qp = query + b * NQ;   // uniform -> scalar loads
#pragma unroll
    for (int q = 0; q < NQ; ++q)
      if (did == qp[q]) atomicAdd(&Sex[q], 1.0f);
  }

  // ---- kernel pooling: s_k = sum_d exp2(Cc*(m-mu)^2), arg = fma(m, fma(Cc,m,bk), gk) ----
  const float Cc = -72.13475204444817f;  // -1/(2*0.1^2*ln2)
  float m[8];
#pragma unroll
  for (int dt = 0; dt < 2; ++dt)
#pragma unroll
    for (int r = 0; r < 4; ++r) m[dt * 4 + r] = acc[dt][r];

#pragma unroll 2
  for (int k = 0; k < 20; ++k) {
    const float mu = fmaf(0.1f, (float)k, -0.95f);
    const float bk = -2.0f * Cc * mu;
    const float gk = Cc * mu * mu;
    float s0 = 0.f, s1 = 0.f;
#pragma unroll
    for (int i = 0; i < 8; i += 2) {
      s0 += __builtin_amdgcn_exp2f(fmaf(m[i    ], fmaf(Cc, m[i    ], bk), gk));
      s1 += __builtin_amdgcn_exp2f(fmaf(m[i + 1], fmaf(Cc, m[i + 1], bk), gk));
    }
    float s = s0 + s1;
    s += __shfl_xor(s, 16);
    s += __shfl_xor(s, 32);
    if (lgrp == 0) Sw[(wave * 16 + lrow) * 20 + k] = s;
  }
  __syncthreads();

  // ---- block reduce -> plain store of ALL 21 kernels for this (b,dq) ----
  for (int i = t; i < NQ * NK; i += 512) {
    const int q = i / NK, k = i % NK;
    float v;
    if (k < 20) {
      const int w0 = q >> 4;
      v = 0.f;
#pragma unroll
      for (int g = 0; g < 4; ++g) v += Sw[((g * 2 + w0) * 16 + (q & 15)) * 20 + k];
    } else {
      v = Sex[q];
    }
    g_Sp[(((size_t)b * 4 + dq) * NQ + q) * NK + k] = v;
  }
}

// ---------------- kernel 3: log1p + MLP ----------------
__global__ __launch_bounds__(64) void knrm_finish(
    const float* __restrict__ w1, const float* __restrict__ b1,
    const float* __restrict__ w2, const float* __restrict__ b2,
    const float* __restrict__ w3, const float* __restrict__ b3,
    float* __restrict__ out)
{
  __shared__ float km[NK], h1[10], h2[5];
  const int b = blockIdx.x, t = threadIdx.x;
  if (t < NK) {
    float s = 0.f;
    for (int q = 0; q < NQ; ++q) {
      float v = 0.f;
#pragma unroll
      for (int g = 0; g < 4; ++g)
        v += g_Sp[(((size_t)b * 4 + g) * NQ + q) * NK + t];
      s += log1pf(v);
    }
    km[t] = s;
  }
  __syncthreads();
  if (t < 10) {
    float a = b1[t];
#pragma unroll 1
    for (int k = 0; k < NK; ++k) a = fmaf(km[k], w1[k * 10 + t], a);
    h1[t] = fmaxf(a, 0.f);
  }
  __syncthreads();
  if (t < 5) {
    float a = b2[t];
#pragma unroll 1
    for (int k = 0; k < 10; ++k) a = fmaf(h1[k], w2[k * 5 + t], a);
    h2[t] = fmaxf(a, 0.f);
  }
  __syncthreads();
  if (t == 0) {
    float a = b3[0];
#pragma unroll 1
    for (int k = 0; k < 5; ++k) a = fmaf(h2[k], w3[k], a);
    out[b] = a;
  }
}

extern "C" void kernel_launch(void* const* d_in, const int* in_sizes, int n_in,
                              void* d_out, int out_size, void* d_ws, size_t ws_size,
                              hipStream_t stream) {
  const int*   query = (const int*)d_in[0];
  const int*   doc   = (const int*)d_in[1];
  const float* emb   = (const float*)d_in[2];
  const float* w1    = (const float*)d_in[3];
  const float* b1    = (const float*)d_in[4];
  const float* w2    = (const float*)d_in[5];
  const float* b2    = (const float*)d_in[6];
  const float* w3    = (const float*)d_in[7];
  const float* b3    = (const float*)d_in[8];
  float* out = (float*)d_out;

  const size_t sh = (size_t)128 * NE * 2    // dtile 32768
                  + (size_t)32 * NE * 2;    // qtile  8192  -> 40960 total
  hipFuncSetAttribute((const void*)knrm_part,
                      hipFuncAttributeMaxDynamicSharedMemorySize, (int)sh);

  // ---- INSTRUMENTATION ROUND: all kernels are idempotent full-overwrite, so
  // repeated launches are bitwise-identical. norm x2, part x3 => per-kernel
  // times become solvable from dur_us, and knrm_part (x3 dispatches) should
  // surface in the rocprof top-5 above the ~40us harness fills.
  norm_kernel<<<dim3(VOCAB / 8), dim3(256), 0, stream>>>(emb);
  norm_kernel<<<dim3(VOCAB / 8), dim3(256), 0, stream>>>(emb);
  knrm_part<<<dim3(NB * 4), dim3(512), sh, stream>>>(query, doc);
  knrm_part<<<dim3(NB * 4), dim3(512), sh, stream>>>(query, doc);
  knrm_part<<<dim3(NB * 4), dim3(512), sh, stream>>>(query, doc);
  knrm_finish<<<dim3(NB), dim3(64), 0, stream>>>(w1, b1, w2, b2, w3, b3, out);
}

// Round 9
// 52.796 us; speedup vs baseline: 2.6108x; 2.6108x over previous
//
#include <hip/hip_runtime.h>
#include <hip/hip_bf16.h>
#include <math.h>

#define NB 512
#define NQ 30
#define ND 512
#define NE 128
#define NK 21
#define VOCAB 50000

typedef __attribute__((ext_vector_type(4))) float f32x4;
typedef __attribute__((ext_vector_type(8))) short short8;

#define AS1C(p) ((const __attribute__((address_space(1))) unsigned int*)(p))
#define AS3C(p) ((__attribute__((address_space(3))) unsigned int*)(p))

// normalized vocab table, bf16 (12.8 MB). Fully rewritten every launch (idempotent).
__device__ unsigned short g_norm[(size_t)VOCAB * NE];
// per-(b,dquarter) partials for ALL 21 kernels incl. exact-match count at k=20.
// Plain stores only, every element rewritten every launch. No atomics, no zeroing.
__device__ float g_Sp[(size_t)NB * 4 * NQ * NK];
// 256B of zeros for padding q-rows 30,31. Never written -> stays zero.
__device__ unsigned short g_zero[NE];

__device__ __forceinline__ unsigned short f2bf(float f) {
  unsigned int x = __builtin_bit_cast(unsigned int, f);
  x = (x + 0x7fffu + ((x >> 16) & 1u)) >> 16;   // RNE
  return (unsigned short)x;
}

// ---------------- kernel 1: normalize vocab to bf16 ----------------
__global__ __launch_bounds__(256) void norm_kernel(const float* __restrict__ emb) {
  const int t = threadIdx.x;
  const int row = blockIdx.x * 8 + (t >> 5);
  const int j = t & 31;
  const float* src = emb + (size_t)row * NE;
  float4 v = *(const float4*)(src + j * 4);
  float ssq = v.x * v.x + v.y * v.y + v.z * v.z + v.w * v.w;
  ssq += __shfl_xor(ssq, 1);
  ssq += __shfl_xor(ssq, 2);
  ssq += __shfl_xor(ssq, 4);
  ssq += __shfl_xor(ssq, 8);
  ssq += __shfl_xor(ssq, 16);
  const float sc = 1.0f / fmaxf(sqrtf(ssq), 1e-12f);
  ushort4 o;
  o.x = f2bf(v.x * sc); o.y = f2bf(v.y * sc);
  o.z = f2bf(v.z * sc); o.w = f2bf(v.w * sc);
  *(ushort4*)(g_norm + (size_t)row * NE + j * 4) = o;
}

// ---------------- kernel 2: partial KNRM (128 doc rows x 32 q per block) ----------------
// 512 threads = 8 waves; wave w: qt=w&1 (16 q), dg=w>>1 (32 d rows).
// LDS: dtile 32KB + qtile 8KB = 40960B -> 4 blocks/CU.
__global__ __launch_bounds__(512, 8) void knrm_part(
    const int* __restrict__ query, const int* __restrict__ doc)
{
  extern __shared__ unsigned char smem_raw[];
  unsigned short* dtile = (unsigned short*)smem_raw;   // [128][128] bf16, slot-swizzled
  unsigned short* qtile = dtile + 128 * NE;            // [32][128]  bf16, slot-swizzled

  const int t = threadIdx.x;
  // XCD swizzle: XCD x gets b in [x*64, (x+1)*64) contiguous. 2048 % 8 == 0 -> bijective.
  const unsigned bid = blockIdx.x;
  const unsigned swz = (bid & 7) * 256 + (bid >> 3);
  const int b  = swz >> 2;
  const int dq = swz & 3;
  const int d0 = dq * 128;

  const int wave = t >> 6, lane = t & 63;
  const int srow4 = lane >> 4, slot = lane & 15;

  // ---- stage 128 doc rows: 4 x global_load_lds(16B), zero VGPR payload ----
#pragma unroll
  for (int rnd = 0; rnd < 4; ++rnd) {
    const int r = rnd * 32 + wave * 4 + srow4;
    const int id = doc[b * ND + d0 + r];
    const unsigned short* src = g_norm + (size_t)id * NE + ((slot ^ (r & 7)) * 8);
    unsigned short* ldst = dtile + (rnd * 32 + wave * 4) * NE;  // wave-uniform
    __builtin_amdgcn_global_load_lds(AS1C(src), AS3C(ldst), 16, 0, 0);
  }
  // ---- stage 32 query rows (30 real + 2 zero), one round ----
  {
    const int qr = wave * 4 + srow4;
    const unsigned short* srcrow =
        (qr < NQ) ? (g_norm + (size_t)query[b * NQ + qr] * NE) : g_zero;
    const unsigned short* src = srcrow + ((slot ^ (qr & 7)) * 8);
    unsigned short* ldst = qtile + (wave * 4) * NE;             // wave-uniform
    __builtin_amdgcn_global_load_lds(AS1C(src), AS3C(ldst), 16, 0, 0);
  }
  __syncthreads();   // drains vmcnt -> tiles complete

  const int lrow = lane & 15, lgrp = lane >> 4;
  const int qt = wave & 1, dg = wave >> 1;

  // ---- mm^T tile: C[d][q]; A and B from swizzled LDS ----
  f32x4 acc[2];
  acc[0] = (f32x4){0.f, 0.f, 0.f, 0.f};
  acc[1] = (f32x4){0.f, 0.f, 0.f, 0.f};
  const int qrow = qt * 16 + lrow;
#pragma unroll
  for (int ks = 0; ks < 4; ++ks) {
    const int qs = (ks * 4 + lgrp) ^ (qrow & 7);
    short8 bq = *(const short8*)(qtile + qrow * NE + qs * 8);
#pragma unroll
    for (int dt = 0; dt < 2; ++dt) {
      const int R = dg * 32 + dt * 16 + lrow;
      const int as = (ks * 4 + lgrp) ^ (R & 7);
      short8 a = *(const short8*)(dtile + R * NE + as * 8);
      acc[dt] = __builtin_amdgcn_mfma_f32_16x16x32_bf16(a, bq, acc[dt], 0, 0, 0);
    }
  }
  __syncthreads();   // LDS tiles consumed -> reuse dtile region

  float* Sw  = (float*)dtile;        // [8 waves][2 lg][16 lrow][20 k] = 20480 B
  float* Sex = Sw + 8 * 2 * 16 * 20; // [32] exact-match counts (block-local)
  if (t < 32) Sex[t] = 0.0f;
  __syncthreads();

  // ---- exact-match kernel (mu=1, sigma=0.001): integer ID equality ----
  if (t < 128) {
    const int did = doc[b * ND + d0 + t];
    const int* qp = query + b * NQ;   // uniform -> scalar loads
#pragma unroll
    for (int q = 0; q < NQ; ++q)
      if (did == qp[q]) atomicAdd(&Sex[q], 1.0f);
  }

  // ---- kernel pooling: s_k = sum_d exp2(Cc*(m-mu)^2), arg = fma(m, fma(Cc,m,bk), gk) ----
  const float Cc = -72.13475204444817f;  // -1/(2*0.1^2*ln2)
  float m[8];
#pragma unroll
  for (int dt = 0; dt < 2; ++dt)
#pragma unroll
    for (int r = 0; r < 4; ++r) m[dt * 4 + r] = acc[dt][r];

#pragma unroll 2
  for (int k = 0; k < 20; ++k) {
    const float mu = fmaf(0.1f, (float)k, -0.95f);
    const float bk = -2.0f * Cc * mu;
    const float gk = Cc * mu * mu;
    float s0 = 0.f, s1 = 0.f;
#pragma unroll
    for (int i = 0; i < 8; i += 2) {
      s0 += __builtin_amdgcn_exp2f(fmaf(m[i    ], fmaf(Cc, m[i    ], bk), gk));
      s1 += __builtin_amdgcn_exp2f(fmaf(m[i + 1], fmaf(Cc, m[i + 1], bk), gk));
    }
    float s = s0 + s1;
    s += __shfl_xor(s, 32);            // one shuffle: fold lgrp{0,2} and {1,3}
    if (lane < 32)                     // lg = lane>>4 in {0,1}
      Sw[((wave * 2 + (lane >> 4)) * 16 + lrow) * 20 + k] = s;
  }
  __syncthreads();

  // ---- block reduce (8 slices per (q,k)) -> plain store for this (b,dq) ----
  for (int i = t; i < NQ * NK; i += 512) {
    const int q = i / NK, k = i % NK;
    float v;
    if (k < 20) {
      const int w0 = q >> 4;
      v = 0.f;
#pragma unroll
      for (int g = 0; g < 4; ++g)
#pragma unroll
        for (int l = 0; l < 2; ++l)
          v += Sw[(((g * 2 + w0) * 2 + l) * 16 + (q & 15)) * 20 + k];
    } else {
      v = Sex[q];
    }
    g_Sp[(((size_t)b * 4 + dq) * NQ + q) * NK + k] = v;
  }
}

// ---------------- kernel 3: log1p + MLP (parallelized) ----------------
// 640 threads: thread i<630 owns one (q,k): 4 coalesced loads + log1p.
// Then 21 threads do a fixed-order 30-add reduce (deterministic).
__global__ __launch_bounds__(640) void knrm_finish(
    const float* __restrict__ w1, const float* __restrict__ b1,
    const float* __restrict__ w2, const float* __restrict__ b2,
    const float* __restrict__ w3, const float* __restrict__ b3,
    float* __restrict__ out)
{
  __shared__ float buf[NQ * NK];
  __shared__ float km[NK], h1[10], h2[5];
  const int b = blockIdx.x, t = threadIdx.x;
  if (t < NQ * NK) {
    const float* base = g_Sp + (size_t)b * 4 * NQ * NK + t;
    float v = base[0] + base[NQ * NK] + base[2 * NQ * NK] + base[3 * NQ * NK];
    buf[t] = log1pf(v);
  }
  __syncthreads();
  if (t < NK) {
    float s = 0.f;
#pragma unroll 1
    for (int q = 0; q < NQ; ++q) s += buf[q * NK + t];
    km[t] = s;
  }
  __syncthreads();
  if (t < 10) {
    float a = b1[t];
#pragma unroll 1
    for (int k = 0; k < NK; ++k) a = fmaf(km[k], w1[k * 10 + t], a);
    h1[t] = fmaxf(a, 0.f);
  }
  __syncthreads();
  if (t < 5) {
    float a = b2[t];
#pragma unroll 1
    for (int k = 0; k < 10; ++k) a = fmaf(h1[k], w2[k * 5 + t], a);
    h2[t] = fmaxf(a, 0.f);
  }
  __syncthreads();
  if (t == 0) {
    float a = b3[0];
#pragma unroll 1
    for (int k = 0; k < 5; ++k) a = fmaf(h2[k], w3[k], a);
    out[b] = a;
  }
}

extern "C" void kernel_launch(void* const* d_in, const int* in_sizes, int n_in,
                              void* d_out, int out_size, void* d_ws, size_t ws_size,
                              hipStream_t stream) {
  const int*   query = (const int*)d_in[0];
  const int*   doc   = (const int*)d_in[1];
  const float* emb   = (const float*)d_in[2];
  const float* w1    = (const float*)d_in[3];
  const float* b1    = (const float*)d_in[4];
  const float* w2    = (const float*)d_in[5];
  const float* b2    = (const float*)d_in[6];
  const float* w3    = (const float*)d_in[7];
  const float* b3    = (const float*)d_in[8];
  float* out = (float*)d_out;

  const size_t sh = (size_t)128 * NE * 2    // dtile 32768
                  + (size_t)32 * NE * 2;    // qtile  8192  -> 40960 total
  hipFuncSetAttribute((const void*)knrm_part,
                      hipFuncAttributeMaxDynamicSharedMemorySize, (int)sh);

  norm_kernel<<<dim3(VOCAB / 8), dim3(256), 0, stream>>>(emb);
  knrm_part<<<dim3(NB * 4), dim3(512), sh, stream>>>(query, doc);
  knrm_finish<<<dim3(NB), dim3(640), 0, stream>>>(w1, b1, w2, b2, w3, b3, out);
}

// Round 10
// 52.660 us; speedup vs baseline: 2.6175x; 1.0026x over previous
//
#include <hip/hip_runtime.h>
#include <hip/hip_bf16.h>
#include <math.h>

#define NB 512
#define NQ 30
#define ND 512
#define NE 128
#define NK 21
#define VOCAB 50000

typedef __attribute__((ext_vector_type(4))) float f32x4;
typedef __attribute__((ext_vector_type(8))) short short8;

#define AS1C(p) ((const __attribute__((address_space(1))) unsigned int*)(p))
#define AS3C(p) ((__attribute__((address_space(3))) unsigned int*)(p))

// normalized vocab table, bf16 (12.8 MB). Fully rewritten every launch (idempotent).
__device__ unsigned short g_norm[(size_t)VOCAB * NE];
// kernel sums S[b][q][k] incl. exact-match at k=20. Plain stores, full overwrite.
__device__ float g_S[(size_t)NB * NQ * NK];
// 256B of zeros for padding q-rows 30,31. Never written -> stays zero.
__device__ unsigned short g_zero[NE];

__device__ __forceinline__ unsigned short f2bf(float f) {
  unsigned int x = __builtin_bit_cast(unsigned int, f);
  x = (x + 0x7fffu + ((x >> 16) & 1u)) >> 16;   // RNE
  return (unsigned short)x;
}

// ---------------- kernel 1: normalize vocab to bf16 ----------------
__global__ __launch_bounds__(256) void norm_kernel(const float* __restrict__ emb) {
  const int t = threadIdx.x;
  const int row = blockIdx.x * 8 + (t >> 5);
  const int j = t & 31;
  const float* src = emb + (size_t)row * NE;
  float4 v = *(const float4*)(src + j * 4);
  float ssq = v.x * v.x + v.y * v.y + v.z * v.z + v.w * v.w;
  ssq += __shfl_xor(ssq, 1);
  ssq += __shfl_xor(ssq, 2);
  ssq += __shfl_xor(ssq, 4);
  ssq += __shfl_xor(ssq, 8);
  ssq += __shfl_xor(ssq, 16);
  const float sc = 1.0f / fmaxf(sqrtf(ssq), 1e-12f);
  ushort4 o;
  o.x = f2bf(v.x * sc); o.y = f2bf(v.y * sc);
  o.z = f2bf(v.z * sc); o.w = f2bf(v.w * sc);
  *(ushort4*)(g_norm + (size_t)row * NE + j * 4) = o;
}

// ---------------- kernel 2: KNRM, one block per b, 4 pipelined d-quarters ----------
// 512 threads = 8 waves; wave w: qt=w&1 (16 q cols), dg=w>>1 (32 d rows/quarter).
// LDS: dtA 32K + dtB 32K + qtile 8K + Sex = 73856 B -> 2 blocks/CU.
__global__ __launch_bounds__(512, 4) void knrm_part(
    const int* __restrict__ query, const int* __restrict__ doc)
{
  extern __shared__ unsigned char smem_raw[];
  unsigned short* dtA   = (unsigned short*)smem_raw;    // [128][128] bf16, slot-swizzled
  unsigned short* dtB   = dtA + 128 * NE;               // [128][128]
  unsigned short* qtile = dtB + 128 * NE;               // [32][128]
  float*          Sex   = (float*)(qtile + 32 * NE);    // [32]

  const int t = threadIdx.x;
  const int b = blockIdx.x;
  const int wave = t >> 6, lane = t & 63;
  const int srow4 = lane >> 4, slot = lane & 15;
  const int lrow = lane & 15, lgrp = lane >> 4;
  const int qt = wave & 1, dg = wave >> 1;

  // ---- stage qtile (once) + doc quarter 0 into dtA; fire-and-forget ----
  {
    const int qr = wave * 4 + srow4;
    const unsigned short* srcrow =
        (qr < NQ) ? (g_norm + (size_t)query[b * NQ + qr] * NE) : g_zero;
    __builtin_amdgcn_global_load_lds(AS1C(srcrow + ((slot ^ (qr & 7)) * 8)),
                                     AS3C(qtile + (wave * 4) * NE), 16, 0, 0);
  }
#pragma unroll
  for (int rnd = 0; rnd < 4; ++rnd) {
    const int r = rnd * 32 + wave * 4 + srow4;
    const int id = doc[b * ND + r];
    __builtin_amdgcn_global_load_lds(
        AS1C(g_norm + (size_t)id * NE + ((slot ^ (r & 7)) * 8)),
        AS3C(dtA + (rnd * 32 + wave * 4) * NE), 16, 0, 0);
  }
  if (t < 32) Sex[t] = 0.0f;
  __syncthreads();   // tiles A+q complete, Sex zeroed

  // ---- exact-match kernel (mu=1, sigma=0.001): integer ID equality ----
  {
    const int did = doc[b * ND + t];
    const int* qp = query + b * NQ;   // uniform -> scalar loads
#pragma unroll 1
    for (int q = 0; q < NQ; ++q)
      if (did == qp[q]) atomicAdd(&Sex[q], 1.0f);   // block-local, +1.0 only
  }

  const float Cc = -72.13475204444817f;  // -1/(2*0.1^2*ln2)
  float s[20];
#pragma unroll
  for (int k = 0; k < 20; ++k) s[k] = 0.0f;

  const int qrow = qt * 16 + lrow;
#pragma unroll 1
  for (int qq = 0; qq < 4; ++qq) {
    unsigned short* cur = (qq & 1) ? dtB : dtA;
    unsigned short* nxt = (qq & 1) ? dtA : dtB;
    // issue next quarter's staging early; lands during this quarter's compute
    if (qq < 3) {
#pragma unroll
      for (int rnd = 0; rnd < 4; ++rnd) {
        const int r = rnd * 32 + wave * 4 + srow4;
        const int id = doc[b * ND + (qq + 1) * 128 + r];
        __builtin_amdgcn_global_load_lds(
            AS1C(g_norm + (size_t)id * NE + ((slot ^ (r & 7)) * 8)),
            AS3C(nxt + (rnd * 32 + wave * 4) * NE), 16, 0, 0);
      }
    }
    // ---- MFMA: C[d][q] tile for this quarter ----
    f32x4 acc[2];
    acc[0] = (f32x4){0.f, 0.f, 0.f, 0.f};
    acc[1] = (f32x4){0.f, 0.f, 0.f, 0.f};
#pragma unroll
    for (int ks = 0; ks < 4; ++ks) {
      const int qs = (ks * 4 + lgrp) ^ (qrow & 7);
      short8 bq = *(const short8*)(qtile + qrow * NE + qs * 8);
#pragma unroll
      for (int dt = 0; dt < 2; ++dt) {
        const int R = dg * 32 + dt * 16 + lrow;
        const int as = (ks * 4 + lgrp) ^ (R & 7);
        short8 a = *(const short8*)(cur + R * NE + as * 8);
        acc[dt] = __builtin_amdgcn_mfma_f32_16x16x32_bf16(a, bq, acc[dt], 0, 0, 0);
      }
    }
    // ---- exp-accumulate into registers (hides the in-flight staging) ----
    float m[8];
#pragma unroll
    for (int dt = 0; dt < 2; ++dt)
#pragma unroll
      for (int r = 0; r < 4; ++r) m[dt * 4 + r] = acc[dt][r];
#pragma unroll
    for (int k = 0; k < 20; ++k) {
      const float mu = fmaf(0.1f, (float)k, -0.95f);
      const float bk = -2.0f * Cc * mu;
      const float gk = Cc * mu * mu;
      float s0 = 0.f, s1 = 0.f;
#pragma unroll
      for (int i = 0; i < 8; i += 2) {
        s0 += __builtin_amdgcn_exp2f(fmaf(m[i    ], fmaf(Cc, m[i    ], bk), gk));
        s1 += __builtin_amdgcn_exp2f(fmaf(m[i + 1], fmaf(Cc, m[i + 1], bk), gk));
      }
      s[k] += s0 + s1;
    }
    __syncthreads();   // drains stage(qq+1); orders buffer reuse
  }

  // ---- final wave reduce: fold lgrp 0..3 -> lanes<16 hold full wave sums ----
#pragma unroll
  for (int k = 0; k < 20; ++k) {
    s[k] += __shfl_xor(s[k], 16);
    s[k] += __shfl_xor(s[k], 32);
  }
  float* Sw = (float*)dtA;   // [8 waves][16 lrow][20 k] = 10240 B (post-barrier reuse)
  if (lgrp == 0) {
#pragma unroll
    for (int k = 0; k < 20; ++k) Sw[(wave * 16 + lrow) * 20 + k] = s[k];
  }
  __syncthreads();

  // ---- block reduce over 4 dg waves -> plain store of S[b][q][k] ----
  for (int i = t; i < NQ * NK; i += 512) {
    const int q = i / NK, k = i % NK;
    float v;
    if (k < 20) {
      const int w0 = q >> 4;
      v = 0.f;
#pragma unroll
      for (int g = 0; g < 4; ++g) v += Sw[((g * 2 + w0) * 16 + (q & 15)) * 20 + k];
    } else {
      v = Sex[q];
    }
    g_S[(size_t)b * NQ * NK + i] = v;
  }
}

// ---------------- kernel 3: log1p + MLP ----------------
__global__ __launch_bounds__(640) void knrm_finish(
    const float* __restrict__ w1, const float* __restrict__ b1,
    const float* __restrict__ w2, const float* __restrict__ b2,
    const float* __restrict__ w3, const float* __restrict__ b3,
    float* __restrict__ out)
{
  __shared__ float buf[NQ * NK];
  __shared__ float km[NK], h1[10], h2[5];
  const int b = blockIdx.x, t = threadIdx.x;
  if (t < NQ * NK) buf[t] = log1pf(g_S[(size_t)b * NQ * NK + t]);
  __syncthreads();
  if (t < NK) {
    float s = 0.f;
#pragma unroll 1
    for (int q = 0; q < NQ; ++q) s += buf[q * NK + t];
    km[t] = s;
  }
  __syncthreads();
  if (t < 10) {
    float a = b1[t];
#pragma unroll 1
    for (int k = 0; k < NK; ++k) a = fmaf(km[k], w1[k * 10 + t], a);
    h1[t] = fmaxf(a, 0.f);
  }
  __syncthreads();
  if (t < 5) {
    float a = b2[t];
#pragma unroll 1
    for (int k = 0; k < 10; ++k) a = fmaf(h1[k], w2[k * 5 + t], a);
    h2[t] = fmaxf(a, 0.f);
  }
  __syncthreads();
  if (t == 0) {
    float a = b3[0];
#pragma unroll 1
    for (int k = 0; k < 5; ++k) a = fmaf(h2[k], w3[k], a);
    out[b] = a;
  }
}

extern "C" void kernel_launch(void* const* d_in, const int* in_sizes, int n_in,
                              void* d_out, int out_size, void* d_ws, size_t ws_size,
                              hipStream_t stream) {
  const int*   query = (const int*)d_in[0];
  const int*   doc   = (const int*)d_in[1];
  const float* emb   = (const float*)d_in[2];
  const float* w1    = (const float*)d_in[3];
  const float* b1    = (const float*)d_in[4];
  const float* w2    = (const float*)d_in[5];
  const float* b2    = (const float*)d_in[6];
  const float* w3    = (const float*)d_in[7];
  const float* b3    = (const float*)d_in[8];
  float* out = (float*)d_out;

  const size_t sh = (size_t)128 * NE * 2 * 2   // dtA + dtB  65536
                  + (size_t)32 * NE * 2        // qtile       8192
                  + 32 * 4;                    // Sex          128  -> 73856
  hipFuncSetAttribute((const void*)knrm_part,
                      hipFuncAttributeMaxDynamicSharedMemorySize, (int)sh);

  norm_kernel<<<dim3(VOCAB / 8), dim3(256), 0, stream>>>(emb);
  knrm_part<<<dim3(NB), dim3(512), sh, stream>>>(query, doc);
  knrm_finish<<<dim3(NB), dim3(640), 0, stream>>>(w1, b1, w2, b2, w3, b3, out);
}

// Round 11
// 40.458 us; speedup vs baseline: 3.4070x; 1.3016x over previous
//
#include <hip/hip_runtime.h>
#include <hip/hip_bf16.h>
#include <math.h>

#define NB 512
#define NQ 30
#define ND 512
#define NE 128
#define NK 21
#define VOCAB 50000

typedef __attribute__((ext_vector_type(4))) float f32x4;
typedef __attribute__((ext_vector_type(2))) float f32x2;
typedef __attribute__((ext_vector_type(8))) short short8;

#define AS1C(p) ((const __attribute__((address_space(1))) unsigned int*)(p))
#define AS3C(p) ((__attribute__((address_space(3))) unsigned int*)(p))

// normalized vocab table, bf16 (12.8 MB). Fully rewritten every launch (idempotent).
__device__ unsigned short g_norm[(size_t)VOCAB * NE];
// 256B of zeros for padding q-rows 30,31. Never written -> stays zero.
__device__ unsigned short g_zero[NE];

__device__ __forceinline__ unsigned short f2bf(float f) {
  unsigned int x = __builtin_bit_cast(unsigned int, f);
  x = (x + 0x7fffu + ((x >> 16) & 1u)) >> 16;   // RNE
  return (unsigned short)x;
}

// ---------------- kernel 1: normalize vocab to bf16 ----------------
__global__ __launch_bounds__(256) void norm_kernel(const float* __restrict__ emb) {
  const int t = threadIdx.x;
  const int row = blockIdx.x * 8 + (t >> 5);
  const int j = t & 31;
  const float* src = emb + (size_t)row * NE;
  float4 v = *(const float4*)(src + j * 4);
  float ssq = v.x * v.x + v.y * v.y + v.z * v.z + v.w * v.w;
  ssq += __shfl_xor(ssq, 1);
  ssq += __shfl_xor(ssq, 2);
  ssq += __shfl_xor(ssq, 4);
  ssq += __shfl_xor(ssq, 8);
  ssq += __shfl_xor(ssq, 16);
  const float sc = 1.0f / fmaxf(sqrtf(ssq), 1e-12f);
  ushort4 o;
  o.x = f2bf(v.x * sc); o.y = f2bf(v.y * sc);
  o.z = f2bf(v.z * sc); o.w = f2bf(v.w * sc);
  *(ushort4*)(g_norm + (size_t)row * NE + j * 4) = o;
}

// ---------------- kernel 2: fused KNRM, one block per b ----------------
// 512 threads = 8 waves; wave w: qt=w&1 (16 q cols), dg=w>>1 (32 d rows/quarter).
// Gaussian pooling via geometric recurrence: E_{k+1} = E_k * W, W *= e^-1,
// restart with exact exp2 every 4 k's (underflow containment).
// LDS: dtA 32K + dtB 32K + qtile 8K + Sex = 73856 B -> 2 blocks/CU.
__global__ __launch_bounds__(512, 4) void knrm_part(
    const int* __restrict__ query, const int* __restrict__ doc,
    const float* __restrict__ w1, const float* __restrict__ b1,
    const float* __restrict__ w2, const float* __restrict__ b2,
    const float* __restrict__ w3, const float* __restrict__ b3,
    float* __restrict__ out)
{
  extern __shared__ unsigned char smem_raw[];
  unsigned short* dtA   = (unsigned short*)smem_raw;    // [128][128] bf16, slot-swizzled
  unsigned short* dtB   = dtA + 128 * NE;               // [128][128]
  unsigned short* qtile = dtB + 128 * NE;               // [32][128]
  float*          Sex   = (float*)(qtile + 32 * NE);    // [32]

  const int t = threadIdx.x;
  const int b = blockIdx.x;
  const int wave = t >> 6, lane = t & 63;
  const int srow4 = lane >> 4, slot = lane & 15;
  const int lrow = lane & 15, lgrp = lane >> 4;
  const int qt = wave & 1, dg = wave >> 1;

  // ---- stage qtile (once) + doc quarter 0 into dtA; fire-and-forget ----
  {
    const int qr = wave * 4 + srow4;
    const unsigned short* srcrow =
        (qr < NQ) ? (g_norm + (size_t)query[b * NQ + qr] * NE) : g_zero;
    __builtin_amdgcn_global_load_lds(AS1C(srcrow + ((slot ^ (qr & 7)) * 8)),
                                     AS3C(qtile + (wave * 4) * NE), 16, 0, 0);
  }
#pragma unroll
  for (int rnd = 0; rnd < 4; ++rnd) {
    const int r = rnd * 32 + wave * 4 + srow4;
    const int id = doc[b * ND + r];
    __builtin_amdgcn_global_load_lds(
        AS1C(g_norm + (size_t)id * NE + ((slot ^ (r & 7)) * 8)),
        AS3C(dtA + (rnd * 32 + wave * 4) * NE), 16, 0, 0);
  }
  if (t < 32) Sex[t] = 0.0f;
  __syncthreads();   // tiles A+q complete, Sex zeroed

  // ---- exact-match kernel (mu=1, sigma=0.001): integer ID equality ----
  {
    const int did = doc[b * ND + t];
    const int* qp = query + b * NQ;   // uniform -> scalar loads
#pragma unroll 1
    for (int q = 0; q < NQ; ++q)
      if (did == qp[q]) atomicAdd(&Sex[q], 1.0f);   // block-local, +1.0 only
  }

  // recurrence constants (Cc*ln2 = -50 exactly: everything is e-clean)
  const float Cc = -72.13475204444817f;           // -50/ln2
  const float ACOEF = 14.426950408889634f;        // 10/ln2 : A = e^{10m}
  const float Rr = 0.36787944117144233f;          // e^-1
  const float Hc[5] = { 8103.083927575384f, 148.4131591025766f,
                        2.718281828459045f, 0.049787068367863944f,
                        0.0009118819655545162f }; // e^{-10*mu_k0 - 0.5}
  const float Bc[5] = { -137.05602888445152f, -79.34822724889299f,
                        -21.64042561333445f, 36.067376022224085f,
                        93.77517765778262f };     // -2*Cc*mu_k0
  const float Gc[5] = { -65.10161372011448f, -21.820762493445572f,
                        -1.6230319210000838f, -4.508422002778011f,
                        -30.47693273877935f };    // Cc*mu_k0^2

  f32x2 s2[20];
#pragma unroll
  for (int k = 0; k < 20; ++k) s2[k] = (f32x2){0.f, 0.f};

  const int qrow = qt * 16 + lrow;
#pragma unroll 1
  for (int qq = 0; qq < 4; ++qq) {
    unsigned short* cur = (qq & 1) ? dtB : dtA;
    unsigned short* nxt = (qq & 1) ? dtA : dtB;
    if (qq < 3) {   // prefetch next quarter during compute
#pragma unroll
      for (int rnd = 0; rnd < 4; ++rnd) {
        const int r = rnd * 32 + wave * 4 + srow4;
        const int id = doc[b * ND + (qq + 1) * 128 + r];
        __builtin_amdgcn_global_load_lds(
            AS1C(g_norm + (size_t)id * NE + ((slot ^ (r & 7)) * 8)),
            AS3C(nxt + (rnd * 32 + wave * 4) * NE), 16, 0, 0);
      }
    }
    // ---- MFMA: C[d][q] tile for this quarter ----
    f32x4 acc[2];
    acc[0] = (f32x4){0.f, 0.f, 0.f, 0.f};
    acc[1] = (f32x4){0.f, 0.f, 0.f, 0.f};
#pragma unroll
    for (int ks = 0; ks < 4; ++ks) {
      const int qs = (ks * 4 + lgrp) ^ (qrow & 7);
      short8 bq = *(const short8*)(qtile + qrow * NE + qs * 8);
#pragma unroll
      for (int dt = 0; dt < 2; ++dt) {
        const int R = dg * 32 + dt * 16 + lrow;
        const int as = (ks * 4 + lgrp) ^ (R & 7);
        short8 a = *(const short8*)(cur + R * NE + as * 8);
        acc[dt] = __builtin_amdgcn_mfma_f32_16x16x32_bf16(a, bq, acc[dt], 0, 0, 0);
      }
    }
    // ---- recurrence pooling: 4 element-pairs, packed f32x2 math ----
#pragma unroll
    for (int dt = 0; dt < 2; ++dt) {
#pragma unroll
      for (int h = 0; h < 2; ++h) {
        f32x2 m2 = { acc[dt][2 * h], acc[dt][2 * h + 1] };
        f32x2 Aarg = m2 * ACOEF;
        f32x2 A2 = { __builtin_amdgcn_exp2f(Aarg.x), __builtin_amdgcn_exp2f(Aarg.y) };
#pragma unroll
        for (int j = 0; j < 5; ++j) {
          f32x2 arg = m2 * (m2 * Cc + Bc[j]) + Gc[j];
          f32x2 E2 = { __builtin_amdgcn_exp2f(arg.x), __builtin_amdgcn_exp2f(arg.y) };
          f32x2 W2 = A2 * Hc[j];
          s2[4 * j]     += E2;
          E2 *= W2; W2 *= Rr;
          s2[4 * j + 1] += E2;
          E2 *= W2; W2 *= Rr;
          s2[4 * j + 2] += E2;
          E2 *= W2;
          s2[4 * j + 3] += E2;
        }
      }
    }
    __syncthreads();   // drains prefetch; orders buffer reuse
  }

  // ---- fold pairs + wave reduce: lanes<16 hold full wave sums ----
  float s[20];
#pragma unroll
  for (int k = 0; k < 20; ++k) {
    s[k] = s2[k].x + s2[k].y;
    s[k] += __shfl_xor(s[k], 16);
    s[k] += __shfl_xor(s[k], 32);
  }
  float* Sw  = (float*)dtA;      // [8 waves][16 lrow][20 k] = 10240 B (dtA dead)
  float* buf = Sw + 2560;        // [NQ*NK] log1p'd sums
  float* km  = buf + 640;        // [21]
  float* h1  = km + 32;          // [10]
  float* h2  = h1 + 16;          // [5]
  if (lgrp == 0) {
#pragma unroll
    for (int k = 0; k < 20; ++k) Sw[(wave * 16 + lrow) * 20 + k] = s[k];
  }
  __syncthreads();

  // ---- block reduce + log1p ----
  for (int i = t; i < NQ * NK; i += 512) {
    const int q = i / NK, k = i % NK;
    float v;
    if (k < 20) {
      const int w0 = q >> 4;
      v = 0.f;
#pragma unroll
      for (int g = 0; g < 4; ++g) v += Sw[((g * 2 + w0) * 16 + (q & 15)) * 20 + k];
    } else {
      v = Sex[q];
    }
    buf[i] = log1pf(v);
  }
  __syncthreads();

  // ---- fused MLP 21->10->5->1 ----
  if (t < NK) {
    float acc0 = 0.f;
#pragma unroll 1
    for (int q = 0; q < NQ; ++q) acc0 += buf[q * NK + t];
    km[t] = acc0;
  }
  __syncthreads();
  if (t < 10) {
    float a = b1[t];
#pragma unroll 1
    for (int k = 0; k < NK; ++k) a = fmaf(km[k], w1[k * 10 + t], a);
    h1[t] = fmaxf(a, 0.f);
  }
  __syncthreads();
  if (t < 5) {
    float a = b2[t];
#pragma unroll 1
    for (int k = 0; k < 10; ++k) a = fmaf(h1[k], w2[k * 5 + t], a);
    h2[t] = fmaxf(a, 0.f);
  }
  __syncthreads();
  if (t == 0) {
    float a = b3[0];
#pragma unroll 1
    for (int k = 0; k < 5; ++k) a = fmaf(h2[k], w3[k], a);
    out[b] = a;
  }
}

extern "C" void kernel_launch(void* const* d_in, const int* in_sizes, int n_in,
                              void* d_out, int out_size, void* d_ws, size_t ws_size,
                              hipStream_t stream) {
  const int*   query = (const int*)d_in[0];
  const int*   doc   = (const int*)d_in[1];
  const float* emb   = (const float*)d_in[2];
  const float* w1    = (const float*)d_in[3];
  const float* b1    = (const float*)d_in[4];
  const float* w2    = (const float*)d_in[5];
  const float* b2    = (const float*)d_in[6];
  const float* w3    = (const float*)d_in[7];
  const float* b3    = (const float*)d_in[8];
  float* out = (float*)d_out;

  const size_t sh = (size_t)128 * NE * 2 * 2   // dtA + dtB  65536
                  + (size_t)32 * NE * 2        // qtile       8192
                  + 32 * 4;                    // Sex          128  -> 73856
  hipFuncSetAttribute((const void*)knrm_part,
                      hipFuncAttributeMaxDynamicSharedMemorySize, (int)sh);

  norm_kernel<<<dim3(VOCAB / 8), dim3(256), 0, stream>>>(emb);
  knrm_part<<<dim3(NB), dim3(512), sh, stream>>>(
      query, doc, w1, b1, w2, b2, w3, b3, out);
}